// Round 1
// 5502.061 us; speedup vs baseline: 1.3293x; 1.3293x over previous
//
#include <hip/hip_runtime.h>

// ResidualSkipRNNForecaster — R7: skewed two-layer pipeline, ONE rendezvous/slot.
//
// Slot s computes L0 step s (v2_0^s) AND L1 step s-1 (v2_1^{s-1}).
// All MFMA operands (v2_0^{s-1} for L0-recurrent AND L1-input, v2_1^{s-2} for
// L1-recurrent) were gathered at the end of slot s-1, so:
//   phase 1 : all 12 MFMAs/wave in one phase (A+C share a0bf fragments)
//   epilog  : waves 0-3 = L0 LN/tanh/publish | waves 4-7 = L1 (parallel)
//   b2+flag : one flag covers both payloads
//   gather  : the single blocking wait, AFTER both publishes -> exposed cost
//             is just the one-way publish->visible latency (the floor the
//             h0^{t-1} -> h0^t recurrence imposes).
// Barriers/slot 5 -> 4; rendezvous/slot 2 -> 1; both LDS-rdy spins removed.
// Protocol safety: parity-2 buffers + monotone flags, same induction as R6
// (writer of par at slot s+2 first observes flags >= s+2, set only after the
// reader's slot-s gather fully completed). Own-stat LDS writes deferred past
// b2 (L1 epilogue reads OLD st0 concurrently). s==0 gather skips the
// never-published L1 payload (NaN guard against garbage workspace).

#define T_SZ 1024
#define DD   64
#define HH   512
#define NCH  8
#define NBLK 16

typedef __attribute__((ext_vector_type(8))) short short8;
typedef __attribute__((ext_vector_type(4))) float f32x4;
typedef unsigned long long ull;

__device__ __forceinline__ unsigned short f2b(float f) {
  unsigned u = __float_as_uint(f);
  u += 0x7fffu + ((u >> 16) & 1u);   // RNE
  return (unsigned short)(u >> 16);
}
__device__ __forceinline__ float b2f(unsigned short s) {
  return __uint_as_float(((unsigned)s) << 16);
}
__device__ __forceinline__ ull packf2(float a, float b) {
  return (ull)__float_as_uint(a) | ((ull)__float_as_uint(b) << 32);
}
__device__ __forceinline__ float unpack_lo(ull u) { return __uint_as_float((unsigned)u); }
__device__ __forceinline__ float unpack_hi(ull u) { return __uint_as_float((unsigned)(u >> 32)); }
__device__ __forceinline__ void st_rlx(ull* p, ull v) {
  __hip_atomic_store(p, v, __ATOMIC_RELAXED, __HIP_MEMORY_SCOPE_AGENT);
}
__device__ __forceinline__ ull ld_rlx(const ull* p) {
  return __hip_atomic_load(p, __ATOMIC_RELAXED, __HIP_MEMORY_SCOPE_AGENT);
}
__device__ __forceinline__ unsigned ld_flag(const unsigned* p) {
  return __hip_atomic_load(p, __ATOMIC_RELAXED, __HIP_MEMORY_SCOPE_AGENT);
}
__device__ __forceinline__ void st_flag(unsigned* p, unsigned v) {
  asm volatile("" ::: "memory");   // keep store after the preceding barrier
  __hip_atomic_store(p, v, __ATOMIC_RELAXED, __HIP_MEMORY_SCOPE_AGENT);
}

__global__ void prep_kernel(const float* __restrict__ Wh0, const float* __restrict__ Wi1,
                            const float* __restrict__ Wh1,
                            const float* __restrict__ bi0, const float* __restrict__ bh0,
                            const float* __restrict__ bi1, const float* __restrict__ bh1,
                            const float* __restrict__ g0, const float* __restrict__ be0,
                            const float* __restrict__ g1, const float* __restrict__ be1,
                            float* __restrict__ cvec, unsigned* __restrict__ flags) {
  int g = blockIdx.x * blockDim.x + threadIdx.x;
  if (g < HH) {
    float uw0 = 0.f, qw0 = 0.f, uw1 = 0.f, qw1 = 0.f, uh1 = 0.f, qh1 = 0.f;
    for (int j = 0; j < HH; ++j) {
      float a = Wh0[j * HH + g], b = Wi1[j * HH + g], d = Wh1[j * HH + g];
      uw0 += g0[j] * a; qw0 += be0[j] * a;
      uw1 += g0[j] * b; qw1 += be0[j] * b;
      uh1 += g1[j] * d; qh1 += be1[j] * d;
    }
    float b0 = bi0[g] + bh0[g], b1 = bi1[g] + bh1[g];
    cvec[0 * HH + g] = b0 + qw0;        // c0 full (t>0)
    cvec[1 * HH + g] = b0;              // c0 init (t==0)
    cvec[2 * HH + g] = b1 + qw1 + qh1;  // c1 full
    cvec[3 * HH + g] = b1 + qw1;        // c1 init
    cvec[4 * HH + g] = uw0;
    cvec[5 * HH + g] = uw1;
    cvec[6 * HH + g] = uh1;
  }
  if (g < 4096) flags[g] = 0;           // 256 blocks x 16 words (flag at +0)
}

__global__ __launch_bounds__(512, 1) void rnn_mfma(
    const float* __restrict__ x,
    const float* __restrict__ Wi0, const float* __restrict__ Wh0,
    const float* __restrict__ Wi1, const float* __restrict__ Wh1,
    const float* __restrict__ cvec,
    const float* __restrict__ g0v, const float* __restrict__ be0v,
    const float* __restrict__ g1v, const float* __restrict__ be1v,
    const float* __restrict__ wfc, const float* __restrict__ bfc,
    ull* __restrict__ pay, ull* __restrict__ pst,
    unsigned* __restrict__ flags, float* __restrict__ out) {

  const int blk = blockIdx.x, group = blk >> 4, p = blk & 15;
  const int tid = threadIdx.x;
  const int wave = tid >> 6, lane = tid & 63;
  const int quad = lane >> 4, m16 = lane & 15;

  // row stride 536 bf16 = 268 words: 16B-aligned rows, banks spread (268%32=12)
  __shared__ unsigned short a0bf[16][536];   // bf16 v2_0^{s-1} (rows 8..15 = 0)
  __shared__ unsigned short a1bf[16][536];   // bf16 v2_1^{s-2}
  __shared__ unsigned short xsb[16][72];     // bf16 x_s (in-place: rewritten after b2)
  __shared__ float partsA[8][8][33];         // v2_0^{s-1} @ (g0.*Wh0)
  __shared__ float partsB[8][8][33];         // v2_1^{s-2} @ (g1.*Wh1)
  __shared__ float partsC[8][8][33];         // v2_0^{s-1} @ (g0.*Wi1)
  __shared__ float partsX[2][8][33];         // x_s @ Wi0 (waves 0,1)
  __shared__ float2 st0[NCH][NBLK];          // (S,Q) of v2_0^{s-1} per publisher
  __shared__ float2 st1[NCH][NBLK];          // (S,Q) of v2_1^{s-2}

  // ---------------- init ----------------
  for (int i = tid; i < 16 * 536; i += 512) {
    (&a0bf[0][0])[i] = 0; (&a1bf[0][0])[i] = 0;
  }
  for (int i = tid; i < 16 * 72; i += 512) (&xsb[0][0])[i] = 0;
  if (tid < NCH * NBLK) {
    (&st0[0][0])[tid] = make_float2(0.f, 0.f);
    (&st1[0][0])[tid] = make_float2(0.f, 0.f);
  }
  { // x_0: thread (wave=chain, lane=d)
    float xv = x[((size_t)(group * NCH + wave) * T_SZ) * DD + lane];
    xsb[wave][lane] = f2b(xv);
  }

  // ---------------- static weight B-fragments (bf16, gamma-folded) --------
  short8 wf0[2][2], wfA[2][2], wfB[2][2], wfx[2];
#pragma unroll
  for (int n = 0; n < 2; ++n)
#pragma unroll
    for (int j = 0; j < 8; ++j) wfx[n][j] = 0;
#pragma unroll
  for (int sl = 0; sl < 2; ++sl)
#pragma unroll
    for (int n = 0; n < 2; ++n) {
      const int col = p * 32 + n * 16 + m16;
#pragma unroll
      for (int j = 0; j < 8; ++j) {
        const int k = wave * 64 + sl * 32 + quad * 8 + j;
        wf0[sl][n][j] = (short)f2b(g0v[k] * Wh0[(size_t)k * HH + col]);
        wfA[sl][n][j] = (short)f2b(g0v[k] * Wi1[(size_t)k * HH + col]);
        wfB[sl][n][j] = (short)f2b(g1v[k] * Wh1[(size_t)k * HH + col]);
      }
    }
  if (wave < 2) {
#pragma unroll
    for (int n = 0; n < 2; ++n) {
      const int col = p * 32 + n * 16 + m16;
#pragma unroll
      for (int j = 0; j < 8; ++j)
        wfx[n][j] = (short)f2b(Wi0[(size_t)(wave * 32 + quad * 8 + j) * HH + col]);
    }
  }

  // epilogue constants — loaded by ALL threads (both wave halves need them)
  const int cl    = lane & 31;
  const int ech   = ((wave & 3) << 1) + (lane >> 5);   // chain 0..7 in each half
  const int col_e = p * 32 + cl;
  const float c0f = cvec[col_e],          c0i = cvec[HH + col_e];
  const float c1f = cvec[2 * HH + col_e], c1i = cvec[3 * HH + col_e];
  const float uw0 = cvec[4 * HH + col_e], uw1 = cvec[5 * HH + col_e];
  const float uh1 = cvec[6 * HH + col_e];
  const float g0c = g0v[col_e], be0c = be0v[col_e];
  const float g1c = g1v[col_e], be1c = be1v[col_e];

  float v2prev0 = 0.f, v2prev1 = 0.f;
  float myS0 = 0.f, myQ0 = 0.f, myS1 = 0.f, myQ1 = 0.f;
  __syncthreads();

  for (int s = 0; s <= T_SZ; ++s) {
    const int par = s & 1;

    // ================= phase 1 : ALL MFMAs (operands from slot s-1) ========
    {
      f32x4 aA0 = {0.f,0.f,0.f,0.f}, aA1 = {0.f,0.f,0.f,0.f};
      f32x4 aB0 = {0.f,0.f,0.f,0.f}, aB1 = {0.f,0.f,0.f,0.f};
      f32x4 aC0 = {0.f,0.f,0.f,0.f}, aC1 = {0.f,0.f,0.f,0.f};
#pragma unroll
      for (int sl = 0; sl < 2; ++sl) {
        const short8 af0 = *(const short8*)&a0bf[m16][wave * 64 + sl * 32 + quad * 8];
        const short8 af1 = *(const short8*)&a1bf[m16][wave * 64 + sl * 32 + quad * 8];
        aA0 = __builtin_amdgcn_mfma_f32_16x16x32_bf16(af0, wf0[sl][0], aA0, 0, 0, 0);
        aA1 = __builtin_amdgcn_mfma_f32_16x16x32_bf16(af0, wf0[sl][1], aA1, 0, 0, 0);
        aC0 = __builtin_amdgcn_mfma_f32_16x16x32_bf16(af0, wfA[sl][0], aC0, 0, 0, 0);
        aC1 = __builtin_amdgcn_mfma_f32_16x16x32_bf16(af0, wfA[sl][1], aC1, 0, 0, 0);
        aB0 = __builtin_amdgcn_mfma_f32_16x16x32_bf16(af1, wfB[sl][0], aB0, 0, 0, 0);
        aB1 = __builtin_amdgcn_mfma_f32_16x16x32_bf16(af1, wfB[sl][1], aB1, 0, 0, 0);
      }
      if (lane < 32) {
#pragma unroll
        for (int r = 0; r < 4; ++r) {
          partsA[wave][quad * 4 + r][m16]      = aA0[r];
          partsA[wave][quad * 4 + r][16 + m16] = aA1[r];
          partsB[wave][quad * 4 + r][m16]      = aB0[r];
          partsB[wave][quad * 4 + r][16 + m16] = aB1[r];
          partsC[wave][quad * 4 + r][m16]      = aC0[r];
          partsC[wave][quad * 4 + r][16 + m16] = aC1[r];
        }
      }
      if (wave < 2) {
        f32x4 ax0 = {0.f,0.f,0.f,0.f}, ax1 = {0.f,0.f,0.f,0.f};
        const short8 xf = *(const short8*)&xsb[m16][wave * 32 + quad * 8];
        ax0 = __builtin_amdgcn_mfma_f32_16x16x32_bf16(xf, wfx[0], ax0, 0, 0, 0);
        ax1 = __builtin_amdgcn_mfma_f32_16x16x32_bf16(xf, wfx[1], ax1, 0, 0, 0);
        if (lane < 32) {
#pragma unroll
          for (int r = 0; r < 4; ++r) {
            partsX[wave][quad * 4 + r][m16]      = ax0[r];
            partsX[wave][quad * 4 + r][16 + m16] = ax1[r];
          }
        }
      }
    }
    __syncthreads();                                    // b1

    // ===== parallel epilogues: waves 0-3 = L0 step s | waves 4-7 = L1 step s-1
    if (wave < 4) {
      if (s < T_SZ) {
        float sH = 0.f;
#pragma unroll
        for (int w = 0; w < 8; ++w) sH += partsA[w][ech][cl];
        const float sX = partsX[0][ech][cl] + partsX[1][ech][cl];
        float m0 = 0.f, r0 = 0.f;
        if (s > 0) {
          float S = 0.f, Q = 0.f;
#pragma unroll
          for (int i = 0; i < NBLK; ++i) { float2 sq = st0[ech][i]; S += sq.x; Q += sq.y; }
          m0 = S * (1.f / HH);
          r0 = 1.f / sqrtf(Q * (1.f / HH) - m0 * m0 + 1e-5f);
        }
        const float z = ((s == 0) ? c0i : c0f) + r0 * sH - r0 * m0 * uw0 + sX;
        const float h0prev = (s == 0) ? 0.f : (v2prev0 - m0) * r0 * g0c + be0c;
        const float v2 = tanhf(z) + h0prev;
        v2prev0 = v2;
        const unsigned vb = f2b(v2);
        a0bf[ech][p * 32 + cl] = (unsigned short)vb;
        const unsigned u01 = vb | (__shfl_down(vb, 1) << 16);
        const unsigned u23 = __shfl_down(u01, 2);
        if ((cl & 3) == 0)
          st_rlx(pay + ((((size_t)blk * 2 + 0) * 2 + par) * NCH + ech) * 8 + (cl >> 2),
                 (ull)u01 | ((ull)u23 << 32));
        float S = v2, Q = v2 * v2;
#pragma unroll
        for (int off = 16; off; off >>= 1) {
          S += __shfl_down(S, off, 32); Q += __shfl_down(Q, off, 32);
        }
        if (cl == 0) {
          myS0 = S; myQ0 = Q;     // LDS write deferred past b2 (st0 still being read)
          st_rlx(pst + (((size_t)blk * 2 + 0) * 2 + par) * NCH + ech, packf2(S, Q));
        }
      }
    } else if (s >= 1) {
      float sB = 0.f, sC = 0.f;
#pragma unroll
      for (int w = 0; w < 8; ++w) { sB += partsB[w][ech][cl]; sC += partsC[w][ech][cl]; }
      float S0 = 0.f, Q0 = 0.f;
#pragma unroll
      for (int i = 0; i < NBLK; ++i) { float2 sq = st0[ech][i]; S0 += sq.x; Q0 += sq.y; }
      const float m0 = S0 * (1.f / HH);
      const float r0 = 1.f / sqrtf(Q0 * (1.f / HH) - m0 * m0 + 1e-5f);
      float m1p = 0.f, r1p = 0.f;
      if (s > 1) {
        float S = 0.f, Q = 0.f;
#pragma unroll
        for (int i = 0; i < NBLK; ++i) { float2 sq = st1[ech][i]; S += sq.x; Q += sq.y; }
        m1p = S * (1.f / HH);
        r1p = 1.f / sqrtf(Q * (1.f / HH) - m1p * m1p + 1e-5f);
      }
      const float z = ((s == 1) ? c1i : c1f) + r0 * sC - r0 * m0 * uw1
                      + r1p * sB - r1p * m1p * uh1;
      const float h1prev = (s == 1) ? 0.f : (v2prev1 - m1p) * r1p * g1c + be1c;
      const float v2 = tanhf(z) + h1prev;
      v2prev1 = v2;
      const unsigned vb = f2b(v2);
      a1bf[ech][p * 32 + cl] = (unsigned short)vb;
      const unsigned u01 = vb | (__shfl_down(vb, 1) << 16);
      const unsigned u23 = __shfl_down(u01, 2);
      if ((cl & 3) == 0)
        st_rlx(pay + ((((size_t)blk * 2 + 1) * 2 + par) * NCH + ech) * 8 + (cl >> 2),
               (ull)u01 | ((ull)u23 << 32));
      float S = v2, Q = v2 * v2;
#pragma unroll
      for (int off = 16; off; off >>= 1) {
        S += __shfl_down(S, off, 32); Q += __shfl_down(Q, off, 32);
      }
      if (cl == 0) {
        myS1 = S; myQ1 = Q;
        st_rlx(pst + (((size_t)blk * 2 + 1) * 2 + par) * NCH + ech, packf2(S, Q));
      }
    }
    __syncthreads();                                    // b2 (drains publishes)
    if (tid == 0) st_flag(flags + blk * 16, (unsigned)(s + 1));
    if (s == T_SZ) break;

    // deferred own-stat LDS writes (read from slot s+1 epilogues onward)
    if (cl == 0) {
      if (wave < 4)       st0[ech][p] = make_float2(myS0, myQ0);
      else if (s >= 1)    st1[ech][p] = make_float2(myS1, myQ1);
    }
    // x prefetch issue (consumed after b3 barrier next slot)
    float xv = 0.f;
    if (s + 1 < T_SZ)
      xv = x[((size_t)(group * NCH + wave) * T_SZ + (s + 1)) * DD + lane];

    // -------- the ONE rendezvous: peers' slot-s publishes --------
    if (tid < 15) {                                      // all pollers in wave 0
      const int pl = tid + (tid >= p);
      const unsigned* pf = flags + (group * NBLK + pl) * 16;
      while (ld_flag(pf) < (unsigned)(s + 1)) __builtin_amdgcn_s_sleep(1);
    }
    __syncthreads();                                    // b_poll

    // -------- combined gather: v2_0^s AND v2_1^{s-1} (skip L1 at s==0) ----
    const int lim = s ? (2 * 15 * 72) : (15 * 72);
#pragma unroll
    for (int it = 0; it < 5; ++it) {
      const int item = tid + it * 512;
      if (item < lim) {
        const int L   = (item >= 1080) ? 1 : 0;
        const int rem = item - L * 1080;
        const int pi  = rem / 72, r2 = rem - pi * 72;
        const int pl  = pi + (pi >= p);
        const size_t pb = ((size_t)(group * NBLK + pl) * 2 + L) * 2 + par;
        if (r2 < 64) {
          const int ch = r2 >> 3, j = r2 & 7;
          ull u = ld_rlx(pay + (pb * NCH + ch) * 8 + j);
          unsigned short (*ab)[536] = L ? a1bf : a0bf;
          *(ull*)&ab[ch][pl * 32 + 4 * j] = u;
        } else {
          const int ch = r2 - 64;
          ull u = ld_rlx(pst + pb * NCH + ch);
          float2 (*stp)[NBLK] = L ? st1 : st0;
          stp[ch][pl] = make_float2(unpack_lo(u), unpack_hi(u));
        }
      }
    }
    if (s + 1 < T_SZ) xsb[wave][lane] = f2b(xv);
    __syncthreads();                                    // b3
  }

  // ============ head (p==0 blocks): out = LN(v2_1^{T-1}).Wfc + bfc ========
  // v2_1^{T-1} published at slot T with par = T&1 = 0.
  if (p == 0) {
    if (tid < 16) {
      const unsigned* pf = flags + (group * NBLK + tid) * 16;
      while (ld_flag(pf) < (unsigned)(T_SZ + 1)) __builtin_amdgcn_s_sleep(1);
    }
    __syncthreads();
    const int c = wave;   // wave handles chain c
    ull su = 0;
    if (lane < 16)
      su = ld_rlx(pst + (((size_t)(group * NBLK + lane) * 2 + 1) * 2 + 0) * NCH + c);
    float S = unpack_lo(su), Q = unpack_hi(su);
#pragma unroll
    for (int off = 32; off; off >>= 1) { S += __shfl_down(S, off); Q += __shfl_down(Q, off); }
    S = __shfl(S, 0); Q = __shfl(Q, 0);
    const float m1 = S * (1.f / HH);
    const float r1 = 1.f / sqrtf(Q * (1.f / HH) - m1 * m1 + 1e-5f);
    float o = 0.f;
#pragma unroll
    for (int it = 0; it < 2; ++it) {
      const int j2 = lane * 2 + it, pl = j2 >> 3, j = j2 & 7;
      ull u = ld_rlx(pay + ((((size_t)(group * NBLK + pl) * 2 + 1) * 2 + 0) * NCH + c) * 8 + j);
#pragma unroll
      for (int q = 0; q < 4; ++q) {
        const int col = pl * 32 + 4 * j + q;
        const float h = (b2f((unsigned short)(u >> (16 * q))) - m1) * r1 * g1v[col] + be1v[col];
        o += h * wfc[col];
      }
    }
#pragma unroll
    for (int off = 32; off; off >>= 1) o += __shfl_down(o, off);
    if (lane == 0) out[group * NCH + c] = o + bfc[0];
  }
}

extern "C" void kernel_launch(void* const* d_in, const int* in_sizes, int n_in,
                              void* d_out, int out_size, void* d_ws, size_t ws_size,
                              hipStream_t stream) {
  const float* x   = (const float*)d_in[0];
  const float* Wi0 = (const float*)d_in[1];
  const float* bi0 = (const float*)d_in[2];
  const float* Wh0 = (const float*)d_in[3];
  const float* bh0 = (const float*)d_in[4];
  const float* g0  = (const float*)d_in[5];
  const float* be0 = (const float*)d_in[6];
  const float* Wi1 = (const float*)d_in[7];
  const float* bi1 = (const float*)d_in[8];
  const float* Wh1 = (const float*)d_in[9];
  const float* bh1 = (const float*)d_in[10];
  const float* g1  = (const float*)d_in[11];
  const float* be1 = (const float*)d_in[12];
  const float* Wfc = (const float*)d_in[13];
  const float* bfc = (const float*)d_in[14];
  float* out = (float*)d_out;

  // ws: cvec 16KB | pay 512KB | pst 64KB | flags 16KB
  char* ws = (char*)d_ws;
  float* cvec     = (float*)(ws);
  ull* pay        = (ull*)(ws + 16384);
  ull* pst        = (ull*)(ws + 16384 + 524288);
  unsigned* flags = (unsigned*)(ws + 16384 + 524288 + 65536);

  prep_kernel<<<256, 256, 0, stream>>>(Wh0, Wi1, Wh1, bi0, bh0, bi1, bh1,
                                       g0, be0, g1, be1, cvec, flags);
  rnn_mfma<<<256, 512, 0, stream>>>(x, Wi0, Wh0, Wi1, Wh1, cvec,
                                    g0, be0, g1, be1, Wfc, bfc,
                                    pay, pst, flags, out);
}

// Round 2
// 3884.694 us; speedup vs baseline: 1.8827x; 1.4163x over previous
//
#include <hip/hip_runtime.h>

// ResidualSkipRNNForecaster — R8: R7 skewed pipeline + register-staged gather
// + per-wave peer polling.
//
// R7 post-mortem: slot = 5.3us vs ~2us structural floor. Missing ~2us matches
// the gather loop serializing 4-5 cross-XCD loads (atomic ld -> immediate LDS
// write forces vmcnt(0) between loads -> 5 x ~900cy round trips). R8:
//   1. gather loads ALL items into registers first (loads pipeline, ONE
//      exposed latency), then writes LDS.
//   2. each wave polls+gathers its own 2 peers (wave7: 1) -> b_poll barrier
//      removed (4 -> 3 barriers/slot), early peers gathered without waiting
//      for the global straggler.
// Protocol unchanged: parity-2 buffers + monotone flags; b3 still orders
// "all peers >= s+1 observed by this block" before any slot-s+1 publish, so
// the R6/R7 overwrite induction holds verbatim.

#define T_SZ 1024
#define DD   64
#define HH   512
#define NCH  8
#define NBLK 16

typedef __attribute__((ext_vector_type(8))) short short8;
typedef __attribute__((ext_vector_type(4))) float f32x4;
typedef unsigned long long ull;

__device__ __forceinline__ unsigned short f2b(float f) {
  unsigned u = __float_as_uint(f);
  u += 0x7fffu + ((u >> 16) & 1u);   // RNE
  return (unsigned short)(u >> 16);
}
__device__ __forceinline__ float b2f(unsigned short s) {
  return __uint_as_float(((unsigned)s) << 16);
}
__device__ __forceinline__ ull packf2(float a, float b) {
  return (ull)__float_as_uint(a) | ((ull)__float_as_uint(b) << 32);
}
__device__ __forceinline__ float unpack_lo(ull u) { return __uint_as_float((unsigned)u); }
__device__ __forceinline__ float unpack_hi(ull u) { return __uint_as_float((unsigned)(u >> 32)); }
__device__ __forceinline__ void st_rlx(ull* p, ull v) {
  __hip_atomic_store(p, v, __ATOMIC_RELAXED, __HIP_MEMORY_SCOPE_AGENT);
}
__device__ __forceinline__ ull ld_rlx(const ull* p) {
  return __hip_atomic_load(p, __ATOMIC_RELAXED, __HIP_MEMORY_SCOPE_AGENT);
}
__device__ __forceinline__ unsigned ld_flag(const unsigned* p) {
  return __hip_atomic_load(p, __ATOMIC_RELAXED, __HIP_MEMORY_SCOPE_AGENT);
}
__device__ __forceinline__ void st_flag(unsigned* p, unsigned v) {
  asm volatile("" ::: "memory");   // keep store after the preceding barrier
  __hip_atomic_store(p, v, __ATOMIC_RELAXED, __HIP_MEMORY_SCOPE_AGENT);
}

__global__ void prep_kernel(const float* __restrict__ Wh0, const float* __restrict__ Wi1,
                            const float* __restrict__ Wh1,
                            const float* __restrict__ bi0, const float* __restrict__ bh0,
                            const float* __restrict__ bi1, const float* __restrict__ bh1,
                            const float* __restrict__ g0, const float* __restrict__ be0,
                            const float* __restrict__ g1, const float* __restrict__ be1,
                            float* __restrict__ cvec, unsigned* __restrict__ flags) {
  int g = blockIdx.x * blockDim.x + threadIdx.x;
  if (g < HH) {
    float uw0 = 0.f, qw0 = 0.f, uw1 = 0.f, qw1 = 0.f, uh1 = 0.f, qh1 = 0.f;
    for (int j = 0; j < HH; ++j) {
      float a = Wh0[j * HH + g], b = Wi1[j * HH + g], d = Wh1[j * HH + g];
      uw0 += g0[j] * a; qw0 += be0[j] * a;
      uw1 += g0[j] * b; qw1 += be0[j] * b;
      uh1 += g1[j] * d; qh1 += be1[j] * d;
    }
    float b0 = bi0[g] + bh0[g], b1 = bi1[g] + bh1[g];
    cvec[0 * HH + g] = b0 + qw0;        // c0 full (t>0)
    cvec[1 * HH + g] = b0;              // c0 init (t==0)
    cvec[2 * HH + g] = b1 + qw1 + qh1;  // c1 full
    cvec[3 * HH + g] = b1 + qw1;        // c1 init
    cvec[4 * HH + g] = uw0;
    cvec[5 * HH + g] = uw1;
    cvec[6 * HH + g] = uh1;
  }
  if (g < 4096) flags[g] = 0;           // 256 blocks x 16 words (flag at +0)
}

__global__ __launch_bounds__(512, 1) void rnn_mfma(
    const float* __restrict__ x,
    const float* __restrict__ Wi0, const float* __restrict__ Wh0,
    const float* __restrict__ Wi1, const float* __restrict__ Wh1,
    const float* __restrict__ cvec,
    const float* __restrict__ g0v, const float* __restrict__ be0v,
    const float* __restrict__ g1v, const float* __restrict__ be1v,
    const float* __restrict__ wfc, const float* __restrict__ bfc,
    ull* __restrict__ pay, ull* __restrict__ pst,
    unsigned* __restrict__ flags, float* __restrict__ out) {

  const int blk = blockIdx.x, group = blk >> 4, p = blk & 15;
  const int tid = threadIdx.x;
  const int wave = tid >> 6, lane = tid & 63;
  const int quad = lane >> 4, m16 = lane & 15;

  // row stride 536 bf16 = 268 words: 16B-aligned rows, banks spread (268%32=12)
  __shared__ unsigned short a0bf[16][536];   // bf16 v2_0^{s-1} (rows 8..15 = 0)
  __shared__ unsigned short a1bf[16][536];   // bf16 v2_1^{s-2}
  __shared__ unsigned short xsb[16][72];     // bf16 x_s (in-place: rewritten after b2)
  __shared__ float partsA[8][8][33];         // v2_0^{s-1} @ (g0.*Wh0)
  __shared__ float partsB[8][8][33];         // v2_1^{s-2} @ (g1.*Wh1)
  __shared__ float partsC[8][8][33];         // v2_0^{s-1} @ (g0.*Wi1)
  __shared__ float partsX[2][8][33];         // x_s @ Wi0 (waves 0,1)
  __shared__ float2 st0[NCH][NBLK];          // (S,Q) of v2_0^{s-1} per publisher
  __shared__ float2 st1[NCH][NBLK];          // (S,Q) of v2_1^{s-2}

  // ---------------- init ----------------
  for (int i = tid; i < 16 * 536; i += 512) {
    (&a0bf[0][0])[i] = 0; (&a1bf[0][0])[i] = 0;
  }
  for (int i = tid; i < 16 * 72; i += 512) (&xsb[0][0])[i] = 0;
  if (tid < NCH * NBLK) {
    (&st0[0][0])[tid] = make_float2(0.f, 0.f);
    (&st1[0][0])[tid] = make_float2(0.f, 0.f);
  }
  { // x_0: thread (wave=chain, lane=d)
    float xv = x[((size_t)(group * NCH + wave) * T_SZ) * DD + lane];
    xsb[wave][lane] = f2b(xv);
  }

  // ---------------- static weight B-fragments (bf16, gamma-folded) --------
  short8 wf0[2][2], wfA[2][2], wfB[2][2], wfx[2];
#pragma unroll
  for (int n = 0; n < 2; ++n)
#pragma unroll
    for (int j = 0; j < 8; ++j) wfx[n][j] = 0;
#pragma unroll
  for (int sl = 0; sl < 2; ++sl)
#pragma unroll
    for (int n = 0; n < 2; ++n) {
      const int col = p * 32 + n * 16 + m16;
#pragma unroll
      for (int j = 0; j < 8; ++j) {
        const int k = wave * 64 + sl * 32 + quad * 8 + j;
        wf0[sl][n][j] = (short)f2b(g0v[k] * Wh0[(size_t)k * HH + col]);
        wfA[sl][n][j] = (short)f2b(g0v[k] * Wi1[(size_t)k * HH + col]);
        wfB[sl][n][j] = (short)f2b(g1v[k] * Wh1[(size_t)k * HH + col]);
      }
    }
  if (wave < 2) {
#pragma unroll
    for (int n = 0; n < 2; ++n) {
      const int col = p * 32 + n * 16 + m16;
#pragma unroll
      for (int j = 0; j < 8; ++j)
        wfx[n][j] = (short)f2b(Wi0[(size_t)(wave * 32 + quad * 8 + j) * HH + col]);
    }
  }

  // epilogue constants — loaded by ALL threads (both wave halves need them)
  const int cl    = lane & 31;
  const int ech   = ((wave & 3) << 1) + (lane >> 5);   // chain 0..7 in each half
  const int col_e = p * 32 + cl;
  const float c0f = cvec[col_e],          c0i = cvec[HH + col_e];
  const float c1f = cvec[2 * HH + col_e], c1i = cvec[3 * HH + col_e];
  const float uw0 = cvec[4 * HH + col_e], uw1 = cvec[5 * HH + col_e];
  const float uh1 = cvec[6 * HH + col_e];
  const float g0c = g0v[col_e], be0c = be0v[col_e];
  const float g1c = g1v[col_e], be1c = be1v[col_e];

  // gather peer assignment: wave w handles peer-slots j0=2w (and j0+1 if <15)
  const int j0   = 2 * wave;
  const bool two = (j0 + 1 < 15);
  const int pg0  = j0 + (j0 >= p);
  const int pg1  = two ? ((j0 + 1) + ((j0 + 1) >= p)) : pg0;
  const unsigned* pf0 = flags + (group * NBLK + pg0) * 16;
  const unsigned* pf1 = flags + (group * NBLK + pg1) * 16;

  float v2prev0 = 0.f, v2prev1 = 0.f;
  float myS0 = 0.f, myQ0 = 0.f, myS1 = 0.f, myQ1 = 0.f;
  __syncthreads();

  for (int s = 0; s <= T_SZ; ++s) {
    const int par = s & 1;

    // ================= phase 1 : ALL MFMAs (operands from slot s-1) ========
    {
      f32x4 aA0 = {0.f,0.f,0.f,0.f}, aA1 = {0.f,0.f,0.f,0.f};
      f32x4 aB0 = {0.f,0.f,0.f,0.f}, aB1 = {0.f,0.f,0.f,0.f};
      f32x4 aC0 = {0.f,0.f,0.f,0.f}, aC1 = {0.f,0.f,0.f,0.f};
#pragma unroll
      for (int sl = 0; sl < 2; ++sl) {
        const short8 af0 = *(const short8*)&a0bf[m16][wave * 64 + sl * 32 + quad * 8];
        const short8 af1 = *(const short8*)&a1bf[m16][wave * 64 + sl * 32 + quad * 8];
        aA0 = __builtin_amdgcn_mfma_f32_16x16x32_bf16(af0, wf0[sl][0], aA0, 0, 0, 0);
        aA1 = __builtin_amdgcn_mfma_f32_16x16x32_bf16(af0, wf0[sl][1], aA1, 0, 0, 0);
        aC0 = __builtin_amdgcn_mfma_f32_16x16x32_bf16(af0, wfA[sl][0], aC0, 0, 0, 0);
        aC1 = __builtin_amdgcn_mfma_f32_16x16x32_bf16(af0, wfA[sl][1], aC1, 0, 0, 0);
        aB0 = __builtin_amdgcn_mfma_f32_16x16x32_bf16(af1, wfB[sl][0], aB0, 0, 0, 0);
        aB1 = __builtin_amdgcn_mfma_f32_16x16x32_bf16(af1, wfB[sl][1], aB1, 0, 0, 0);
      }
      if (lane < 32) {
#pragma unroll
        for (int r = 0; r < 4; ++r) {
          partsA[wave][quad * 4 + r][m16]      = aA0[r];
          partsA[wave][quad * 4 + r][16 + m16] = aA1[r];
          partsB[wave][quad * 4 + r][m16]      = aB0[r];
          partsB[wave][quad * 4 + r][16 + m16] = aB1[r];
          partsC[wave][quad * 4 + r][m16]      = aC0[r];
          partsC[wave][quad * 4 + r][16 + m16] = aC1[r];
        }
      }
      if (wave < 2) {
        f32x4 ax0 = {0.f,0.f,0.f,0.f}, ax1 = {0.f,0.f,0.f,0.f};
        const short8 xf = *(const short8*)&xsb[m16][wave * 32 + quad * 8];
        ax0 = __builtin_amdgcn_mfma_f32_16x16x32_bf16(xf, wfx[0], ax0, 0, 0, 0);
        ax1 = __builtin_amdgcn_mfma_f32_16x16x32_bf16(xf, wfx[1], ax1, 0, 0, 0);
        if (lane < 32) {
#pragma unroll
          for (int r = 0; r < 4; ++r) {
            partsX[wave][quad * 4 + r][m16]      = ax0[r];
            partsX[wave][quad * 4 + r][16 + m16] = ax1[r];
          }
        }
      }
    }
    __syncthreads();                                    // b1

    // ===== parallel epilogues: waves 0-3 = L0 step s | waves 4-7 = L1 step s-1
    if (wave < 4) {
      if (s < T_SZ) {
        float sH = 0.f;
#pragma unroll
        for (int w = 0; w < 8; ++w) sH += partsA[w][ech][cl];
        const float sX = partsX[0][ech][cl] + partsX[1][ech][cl];
        float m0 = 0.f, r0 = 0.f;
        if (s > 0) {
          float S = 0.f, Q = 0.f;
#pragma unroll
          for (int i = 0; i < NBLK; ++i) { float2 sq = st0[ech][i]; S += sq.x; Q += sq.y; }
          m0 = S * (1.f / HH);
          r0 = 1.f / sqrtf(Q * (1.f / HH) - m0 * m0 + 1e-5f);
        }
        const float z = ((s == 0) ? c0i : c0f) + r0 * sH - r0 * m0 * uw0 + sX;
        const float h0prev = (s == 0) ? 0.f : (v2prev0 - m0) * r0 * g0c + be0c;
        const float v2 = tanhf(z) + h0prev;
        v2prev0 = v2;
        const unsigned vb = f2b(v2);
        a0bf[ech][p * 32 + cl] = (unsigned short)vb;
        const unsigned u01 = vb | (__shfl_down(vb, 1) << 16);
        const unsigned u23 = __shfl_down(u01, 2);
        if ((cl & 3) == 0)
          st_rlx(pay + ((((size_t)blk * 2 + 0) * 2 + par) * NCH + ech) * 8 + (cl >> 2),
                 (ull)u01 | ((ull)u23 << 32));
        float S = v2, Q = v2 * v2;
#pragma unroll
        for (int off = 16; off; off >>= 1) {
          S += __shfl_down(S, off, 32); Q += __shfl_down(Q, off, 32);
        }
        if (cl == 0) {
          myS0 = S; myQ0 = Q;     // LDS write deferred past b2 (st0 still being read)
          st_rlx(pst + (((size_t)blk * 2 + 0) * 2 + par) * NCH + ech, packf2(S, Q));
        }
      }
    } else if (s >= 1) {
      float sB = 0.f, sC = 0.f;
#pragma unroll
      for (int w = 0; w < 8; ++w) { sB += partsB[w][ech][cl]; sC += partsC[w][ech][cl]; }
      float S0 = 0.f, Q0 = 0.f;
#pragma unroll
      for (int i = 0; i < NBLK; ++i) { float2 sq = st0[ech][i]; S0 += sq.x; Q0 += sq.y; }
      const float m0 = S0 * (1.f / HH);
      const float r0 = 1.f / sqrtf(Q0 * (1.f / HH) - m0 * m0 + 1e-5f);
      float m1p = 0.f, r1p = 0.f;
      if (s > 1) {
        float S = 0.f, Q = 0.f;
#pragma unroll
        for (int i = 0; i < NBLK; ++i) { float2 sq = st1[ech][i]; S += sq.x; Q += sq.y; }
        m1p = S * (1.f / HH);
        r1p = 1.f / sqrtf(Q * (1.f / HH) - m1p * m1p + 1e-5f);
      }
      const float z = ((s == 1) ? c1i : c1f) + r0 * sC - r0 * m0 * uw1
                      + r1p * sB - r1p * m1p * uh1;
      const float h1prev = (s == 1) ? 0.f : (v2prev1 - m1p) * r1p * g1c + be1c;
      const float v2 = tanhf(z) + h1prev;
      v2prev1 = v2;
      const unsigned vb = f2b(v2);
      a1bf[ech][p * 32 + cl] = (unsigned short)vb;
      const unsigned u01 = vb | (__shfl_down(vb, 1) << 16);
      const unsigned u23 = __shfl_down(u01, 2);
      if ((cl & 3) == 0)
        st_rlx(pay + ((((size_t)blk * 2 + 1) * 2 + par) * NCH + ech) * 8 + (cl >> 2),
               (ull)u01 | ((ull)u23 << 32));
      float S = v2, Q = v2 * v2;
#pragma unroll
      for (int off = 16; off; off >>= 1) {
        S += __shfl_down(S, off, 32); Q += __shfl_down(Q, off, 32);
      }
      if (cl == 0) {
        myS1 = S; myQ1 = Q;
        st_rlx(pst + (((size_t)blk * 2 + 1) * 2 + par) * NCH + ech, packf2(S, Q));
      }
    }
    __syncthreads();                                    // b2 (drains publishes)
    if (tid == 0) st_flag(flags + blk * 16, (unsigned)(s + 1));
    if (s == T_SZ) break;

    // deferred own-stat LDS writes (read from slot s+1 epilogues onward)
    if (cl == 0) {
      if (wave < 4)       st0[ech][p] = make_float2(myS0, myQ0);
      else if (s >= 1)    st1[ech][p] = make_float2(myS1, myQ1);
    }
    // x prefetch issue (consumed after b3 barrier next slot)
    float xv = 0.f;
    if (s + 1 < T_SZ)
      xv = x[((size_t)(group * NCH + wave) * T_SZ + (s + 1)) * DD + lane];

    // -------- per-wave rendezvous: this wave's 1-2 peers only --------
    while (ld_flag(pf0) < (unsigned)(s + 1)) __builtin_amdgcn_s_sleep(1);
    if (two)
      while (ld_flag(pf1) < (unsigned)(s + 1)) __builtin_amdgcn_s_sleep(1);

    // -------- register-staged gather: issue ALL loads, then write LDS ------
    // per-peer layout (144 items): [0,64)=L0 pay, [64,72)=L0 st,
    // [72,136)=L1 pay, [136,144)=L1 st. At s==0 the L1 half is skipped
    // (never published; a1bf/st1 stay zero).
    {
      ull  tv[5];
      bool va[5];
      int  vr2[5], vpl[5];
#pragma unroll
      for (int k = 0; k < 5; ++k) {
        const int li  = lane + (k << 6);
        const int lim = two ? 288 : 144;
        const int jr  = (li >= 144) ? 1 : 0;
        const int r2  = li - 144 * jr;
        const int pl  = jr ? pg1 : pg0;
        const bool v  = (li < lim) && (s > 0 || r2 < 72);
        va[k] = v; vr2[k] = r2; vpl[k] = pl;
        tv[k] = 0;
        if (v) {
          const int L  = (r2 >= 72) ? 1 : 0;
          const int rr = r2 - 72 * L;
          const size_t pb = ((size_t)(group * NBLK + pl) * 2 + L) * 2 + par;
          const ull* ap = (rr < 64) ? (pay + (pb * NCH + (rr >> 3)) * 8 + (rr & 7))
                                    : (pst + pb * NCH + (rr - 64));
          tv[k] = ld_rlx(ap);
        }
      }
#pragma unroll
      for (int k = 0; k < 5; ++k) {
        if (va[k]) {
          const int r2 = vr2[k], pl = vpl[k];
          const int L  = (r2 >= 72) ? 1 : 0;
          const int rr = r2 - 72 * L;
          if (rr < 64) {
            unsigned short (*ab)[536] = L ? a1bf : a0bf;
            *(ull*)&ab[rr >> 3][pl * 32 + 4 * (rr & 7)] = tv[k];
          } else {
            float2 (*stp)[NBLK] = L ? st1 : st0;
            stp[rr - 64][pl] = make_float2(unpack_lo(tv[k]), unpack_hi(tv[k]));
          }
        }
      }
    }
    if (s + 1 < T_SZ) xsb[wave][lane] = f2b(xv);
    __syncthreads();                                    // b3
  }

  // ============ head (p==0 blocks): out = LN(v2_1^{T-1}).Wfc + bfc ========
  // v2_1^{T-1} published at slot T with par = T&1 = 0.
  if (p == 0) {
    if (tid < 16) {
      const unsigned* pf = flags + (group * NBLK + tid) * 16;
      while (ld_flag(pf) < (unsigned)(T_SZ + 1)) __builtin_amdgcn_s_sleep(1);
    }
    __syncthreads();
    const int c = wave;   // wave handles chain c
    ull su = 0;
    if (lane < 16)
      su = ld_rlx(pst + (((size_t)(group * NBLK + lane) * 2 + 1) * 2 + 0) * NCH + c);
    float S = unpack_lo(su), Q = unpack_hi(su);
#pragma unroll
    for (int off = 32; off; off >>= 1) { S += __shfl_down(S, off); Q += __shfl_down(Q, off); }
    S = __shfl(S, 0); Q = __shfl(Q, 0);
    const float m1 = S * (1.f / HH);
    const float r1 = 1.f / sqrtf(Q * (1.f / HH) - m1 * m1 + 1e-5f);
    float o = 0.f;
#pragma unroll
    for (int it = 0; it < 2; ++it) {
      const int j2 = lane * 2 + it, pl = j2 >> 3, j = j2 & 7;
      ull u = ld_rlx(pay + ((((size_t)(group * NBLK + pl) * 2 + 1) * 2 + 0) * NCH + c) * 8 + j);
#pragma unroll
      for (int q = 0; q < 4; ++q) {
        const int col = pl * 32 + 4 * j + q;
        const float h = (b2f((unsigned short)(u >> (16 * q))) - m1) * r1 * g1v[col] + be1v[col];
        o += h * wfc[col];
      }
    }
#pragma unroll
    for (int off = 32; off; off >>= 1) o += __shfl_down(o, off);
    if (lane == 0) out[group * NCH + c] = o + bfc[0];
  }
}

extern "C" void kernel_launch(void* const* d_in, const int* in_sizes, int n_in,
                              void* d_out, int out_size, void* d_ws, size_t ws_size,
                              hipStream_t stream) {
  const float* x   = (const float*)d_in[0];
  const float* Wi0 = (const float*)d_in[1];
  const float* bi0 = (const float*)d_in[2];
  const float* Wh0 = (const float*)d_in[3];
  const float* bh0 = (const float*)d_in[4];
  const float* g0  = (const float*)d_in[5];
  const float* be0 = (const float*)d_in[6];
  const float* Wi1 = (const float*)d_in[7];
  const float* bi1 = (const float*)d_in[8];
  const float* Wh1 = (const float*)d_in[9];
  const float* bh1 = (const float*)d_in[10];
  const float* g1  = (const float*)d_in[11];
  const float* be1 = (const float*)d_in[12];
  const float* Wfc = (const float*)d_in[13];
  const float* bfc = (const float*)d_in[14];
  float* out = (float*)d_out;

  // ws: cvec 16KB | pay 512KB | pst 64KB | flags 16KB
  char* ws = (char*)d_ws;
  float* cvec     = (float*)(ws);
  ull* pay        = (ull*)(ws + 16384);
  ull* pst        = (ull*)(ws + 16384 + 524288);
  unsigned* flags = (unsigned*)(ws + 16384 + 524288 + 65536);

  prep_kernel<<<256, 256, 0, stream>>>(Wh0, Wi1, Wh1, bi0, bh0, bi1, bh1,
                                       g0, be0, g1, be1, cvec, flags);
  rnn_mfma<<<256, 512, 0, stream>>>(x, Wi0, Wh0, Wi1, Wh1, cvec,
                                    g0, be0, g1, be1, Wfc, bfc,
                                    pay, pst, flags, out);
}

// Round 3
// 3158.747 us; speedup vs baseline: 2.3154x; 1.2298x over previous
//
#include <hip/hip_runtime.h>

// ResidualSkipRNNForecaster — R9: R8 + VALU-diet on the critical path.
//
// R8 post-mortem: 3.74us/slot, VALUBusy 28.7% (~1.07us/slot of VALU issue),
// much of it between b1 and b2. R9:
//   1. LN-stats (m0/r0 from st0, m1p/r1p from st1) HOISTED to the top of the
//      slot — st0/st1 are complete there (prev slot's gather + deferred write,
//      sealed by b3) and stable until this slot's gather. Overlaps MFMA.
//   2. fast_tanh = 1 - 2*rcp(exp2(2log2e*z)+1): 5 VALU ops vs ~25 (exact same
//      function; ~1e-7 abs err, far below bf16 payload rounding).
//   3. Gather addresses precomputed per-thread for BOTH parities (registers,
//      statically indexed) -> per-slot gather is 5 loads + 5 ull LDS stores,
//      zero int ALU. Stats float2 and payload ull are both 8B stores.
//   4. Publish pay/pst addresses precomputed (par-select); x pointer strided;
//      rsqf for LN rsqrt.
// Protocol/barriers/flags IDENTICAL to R8 — no new race modes.

#define T_SZ 1024
#define DD   64
#define HH   512
#define NCH  8
#define NBLK 16

typedef __attribute__((ext_vector_type(8))) short short8;
typedef __attribute__((ext_vector_type(4))) float f32x4;
typedef unsigned long long ull;

__device__ __forceinline__ unsigned short f2b(float f) {
  unsigned u = __float_as_uint(f);
  u += 0x7fffu + ((u >> 16) & 1u);   // RNE
  return (unsigned short)(u >> 16);
}
__device__ __forceinline__ float b2f(unsigned short s) {
  return __uint_as_float(((unsigned)s) << 16);
}
__device__ __forceinline__ ull packf2(float a, float b) {
  return (ull)__float_as_uint(a) | ((ull)__float_as_uint(b) << 32);
}
__device__ __forceinline__ float unpack_lo(ull u) { return __uint_as_float((unsigned)u); }
__device__ __forceinline__ float unpack_hi(ull u) { return __uint_as_float((unsigned)(u >> 32)); }
__device__ __forceinline__ void st_rlx(ull* p, ull v) {
  __hip_atomic_store(p, v, __ATOMIC_RELAXED, __HIP_MEMORY_SCOPE_AGENT);
}
__device__ __forceinline__ ull ld_rlx(const ull* p) {
  return __hip_atomic_load(p, __ATOMIC_RELAXED, __HIP_MEMORY_SCOPE_AGENT);
}
__device__ __forceinline__ unsigned ld_flag(const unsigned* p) {
  return __hip_atomic_load(p, __ATOMIC_RELAXED, __HIP_MEMORY_SCOPE_AGENT);
}
__device__ __forceinline__ void st_flag(unsigned* p, unsigned v) {
  asm volatile("" ::: "memory");   // keep store after the preceding barrier
  __hip_atomic_store(p, v, __ATOMIC_RELAXED, __HIP_MEMORY_SCOPE_AGENT);
}
// tanh(z) = 1 - 2/(e^{2z}+1), exact; exp2+rcp HW approx (~1e-7 abs err).
__device__ __forceinline__ float fast_tanh(float z) {
  const float e = __builtin_amdgcn_exp2f(z * 2.885390081777927f);  // e^{2z}
  return 1.f - 2.f * __builtin_amdgcn_rcpf(e + 1.f);
}

__global__ void prep_kernel(const float* __restrict__ Wh0, const float* __restrict__ Wi1,
                            const float* __restrict__ Wh1,
                            const float* __restrict__ bi0, const float* __restrict__ bh0,
                            const float* __restrict__ bi1, const float* __restrict__ bh1,
                            const float* __restrict__ g0, const float* __restrict__ be0,
                            const float* __restrict__ g1, const float* __restrict__ be1,
                            float* __restrict__ cvec, unsigned* __restrict__ flags) {
  int g = blockIdx.x * blockDim.x + threadIdx.x;
  if (g < HH) {
    float uw0 = 0.f, qw0 = 0.f, uw1 = 0.f, qw1 = 0.f, uh1 = 0.f, qh1 = 0.f;
    for (int j = 0; j < HH; ++j) {
      float a = Wh0[j * HH + g], b = Wi1[j * HH + g], d = Wh1[j * HH + g];
      uw0 += g0[j] * a; qw0 += be0[j] * a;
      uw1 += g0[j] * b; qw1 += be0[j] * b;
      uh1 += g1[j] * d; qh1 += be1[j] * d;
    }
    float b0 = bi0[g] + bh0[g], b1 = bi1[g] + bh1[g];
    cvec[0 * HH + g] = b0 + qw0;        // c0 full (t>0)
    cvec[1 * HH + g] = b0;              // c0 init (t==0)
    cvec[2 * HH + g] = b1 + qw1 + qh1;  // c1 full
    cvec[3 * HH + g] = b1 + qw1;        // c1 init
    cvec[4 * HH + g] = uw0;
    cvec[5 * HH + g] = uw1;
    cvec[6 * HH + g] = uh1;
  }
  if (g < 4096) flags[g] = 0;           // 256 blocks x 16 words (flag at +0)
}

__global__ __launch_bounds__(512, 1) void rnn_mfma(
    const float* __restrict__ x,
    const float* __restrict__ Wi0, const float* __restrict__ Wh0,
    const float* __restrict__ Wi1, const float* __restrict__ Wh1,
    const float* __restrict__ cvec,
    const float* __restrict__ g0v, const float* __restrict__ be0v,
    const float* __restrict__ g1v, const float* __restrict__ be1v,
    const float* __restrict__ wfc, const float* __restrict__ bfc,
    ull* __restrict__ pay, ull* __restrict__ pst,
    unsigned* __restrict__ flags, float* __restrict__ out) {

  const int blk = blockIdx.x, group = blk >> 4, p = blk & 15;
  const int tid = threadIdx.x;
  const int wave = tid >> 6, lane = tid & 63;
  const int quad = lane >> 4, m16 = lane & 15;

  // row stride 536 bf16 = 268 words: 16B-aligned rows, banks spread (268%32=12)
  __shared__ unsigned short a0bf[16][536];   // bf16 v2_0^{s-1} (rows 8..15 = 0)
  __shared__ unsigned short a1bf[16][536];   // bf16 v2_1^{s-2}
  __shared__ unsigned short xsb[16][72];     // bf16 x_s (in-place: rewritten after b2)
  __shared__ float partsA[8][8][33];         // v2_0^{s-1} @ (g0.*Wh0)
  __shared__ float partsB[8][8][33];         // v2_1^{s-2} @ (g1.*Wh1)
  __shared__ float partsC[8][8][33];         // v2_0^{s-1} @ (g0.*Wi1)
  __shared__ float partsX[2][8][33];         // x_s @ Wi0 (waves 0,1)
  __shared__ float2 st0[NCH][NBLK];          // (S,Q) of v2_0^{s-1} per publisher
  __shared__ float2 st1[NCH][NBLK];          // (S,Q) of v2_1^{s-2}

  // ---------------- init ----------------
  for (int i = tid; i < 16 * 536; i += 512) {
    (&a0bf[0][0])[i] = 0; (&a1bf[0][0])[i] = 0;
  }
  for (int i = tid; i < 16 * 72; i += 512) (&xsb[0][0])[i] = 0;
  if (tid < NCH * NBLK) {
    (&st0[0][0])[tid] = make_float2(0.f, 0.f);
    (&st1[0][0])[tid] = make_float2(0.f, 0.f);
  }
  { // x_0: thread (wave=chain, lane=d)
    float xv = x[((size_t)(group * NCH + wave) * T_SZ) * DD + lane];
    xsb[wave][lane] = f2b(xv);
  }

  // ---------------- static weight B-fragments (bf16, gamma-folded) --------
  short8 wf0[2][2], wfA[2][2], wfB[2][2], wfx[2];
#pragma unroll
  for (int n = 0; n < 2; ++n)
#pragma unroll
    for (int j = 0; j < 8; ++j) wfx[n][j] = 0;
#pragma unroll
  for (int sl = 0; sl < 2; ++sl)
#pragma unroll
    for (int n = 0; n < 2; ++n) {
      const int col = p * 32 + n * 16 + m16;
#pragma unroll
      for (int j = 0; j < 8; ++j) {
        const int k = wave * 64 + sl * 32 + quad * 8 + j;
        wf0[sl][n][j] = (short)f2b(g0v[k] * Wh0[(size_t)k * HH + col]);
        wfA[sl][n][j] = (short)f2b(g0v[k] * Wi1[(size_t)k * HH + col]);
        wfB[sl][n][j] = (short)f2b(g1v[k] * Wh1[(size_t)k * HH + col]);
      }
    }
  if (wave < 2) {
#pragma unroll
    for (int n = 0; n < 2; ++n) {
      const int col = p * 32 + n * 16 + m16;
#pragma unroll
      for (int j = 0; j < 8; ++j)
        wfx[n][j] = (short)f2b(Wi0[(size_t)(wave * 32 + quad * 8 + j) * HH + col]);
    }
  }

  // epilogue constants — loaded by ALL threads (both wave halves need them)
  const int cl    = lane & 31;
  const int ech   = ((wave & 3) << 1) + (lane >> 5);   // chain 0..7 in each half
  const int col_e = p * 32 + cl;
  const float c0f = cvec[col_e],          c0i = cvec[HH + col_e];
  const float c1f = cvec[2 * HH + col_e], c1i = cvec[3 * HH + col_e];
  const float uw0 = cvec[4 * HH + col_e], uw1 = cvec[5 * HH + col_e];
  const float uh1 = cvec[6 * HH + col_e];
  const float g0c = g0v[col_e], be0c = be0v[col_e];
  const float g1c = g1v[col_e], be1c = be1v[col_e];

  // publish addresses (this thread's layer half), both parities
  const int Lp = (wave >= 4) ? 1 : 0;
  ull* const pubpay0 = pay + ((((size_t)blk * 2 + Lp) * 2 + 0) * NCH + ech) * 8 + (cl >> 2);
  ull* const pubpay1 = pubpay0 + (size_t)NCH * 8;
  ull* const pubpst0 = pst + (((size_t)blk * 2 + Lp) * 2 + 0) * NCH + ech;
  ull* const pubpst1 = pubpst0 + NCH;
  unsigned short* const ep_lds = &((wave < 4) ? a0bf : a1bf)[ech][p * 32 + cl];

  // gather peer assignment: wave w handles peer-slots j0=2w (and j0+1 if <15)
  const int j0   = 2 * wave;
  const bool two = (j0 + 1 < 15);
  const int pg0  = j0 + (j0 >= p);
  const int pg1  = two ? ((j0 + 1) + ((j0 + 1) >= p)) : pg0;
  const unsigned* pf0 = flags + (group * NBLK + pg0) * 16;
  const unsigned* pf1 = flags + (group * NBLK + pg1) * 16;

  // -------- precomputed gather plan (both parities; statically indexed) ----
  // per-peer layout (144 items): [0,64)=L0 pay, [64,72)=L0 st,
  // [72,136)=L1 pay, [136,144)=L1 st.
  const ull* gp0[5]; const ull* gp1[5]; ull* glw[5]; bool gv[5], gva0[5];
#pragma unroll
  for (int k = 0; k < 5; ++k) {
    const int li  = lane + (k << 6);
    const int lim = two ? 288 : 144;
    const int jr  = (li >= 144) ? 1 : 0;
    const int r2  = li - 144 * jr;
    const int pl  = jr ? pg1 : pg0;
    gv[k]  = (li < lim);
    gva0[k] = gv[k] && (r2 < 72);        // at s==0 only the L0 half exists
    const int L  = (r2 >= 72) ? 1 : 0;
    const int rr = r2 - 72 * L;
    const size_t pb = ((size_t)(group * NBLK + pl) * 2 + L) * 2;   // + par
    if (rr < 64) {
      gp0[k] = pay + ((pb + 0) * NCH + (rr >> 3)) * 8 + (rr & 7);
      gp1[k] = pay + ((pb + 1) * NCH + (rr >> 3)) * 8 + (rr & 7);
      glw[k] = (ull*)&(L ? a1bf : a0bf)[rr >> 3][pl * 32 + 4 * (rr & 7)];
    } else {
      gp0[k] = pst + (pb + 0) * NCH + (rr - 64);
      gp1[k] = pst + (pb + 1) * NCH + (rr - 64);
      glw[k] = (ull*)&(L ? st1 : st0)[rr - 64][pl];   // float2 = 8B, same bits
    }
  }

  const float* xptr = x + ((size_t)(group * NCH + wave) * T_SZ + 1) * DD + lane;

  float v2prev0 = 0.f, v2prev1 = 0.f;
  float myS0 = 0.f, myQ0 = 0.f, myS1 = 0.f, myQ1 = 0.f;
  __syncthreads();

  for (int s = 0; s <= T_SZ; ++s) {
    const int par = s & 1;

    // ---- hoisted LN stats (st0/st1 sealed by prev b3, stable till gather) --
    float m0 = 0.f, r0 = 0.f, m1p = 0.f, r1p = 0.f;
    if (s > 0) {
      float S = 0.f, Q = 0.f;
#pragma unroll
      for (int i = 0; i < NBLK; ++i) { float2 sq = st0[ech][i]; S += sq.x; Q += sq.y; }
      m0 = S * (1.f / HH);
      r0 = __builtin_amdgcn_rsqf(Q * (1.f / HH) - m0 * m0 + 1e-5f);
    }
    if (wave >= 4 && s > 1) {
      float S = 0.f, Q = 0.f;
#pragma unroll
      for (int i = 0; i < NBLK; ++i) { float2 sq = st1[ech][i]; S += sq.x; Q += sq.y; }
      m1p = S * (1.f / HH);
      r1p = __builtin_amdgcn_rsqf(Q * (1.f / HH) - m1p * m1p + 1e-5f);
    }

    // ================= phase 1 : ALL MFMAs (operands from slot s-1) ========
    {
      f32x4 aA0 = {0.f,0.f,0.f,0.f}, aA1 = {0.f,0.f,0.f,0.f};
      f32x4 aB0 = {0.f,0.f,0.f,0.f}, aB1 = {0.f,0.f,0.f,0.f};
      f32x4 aC0 = {0.f,0.f,0.f,0.f}, aC1 = {0.f,0.f,0.f,0.f};
#pragma unroll
      for (int sl = 0; sl < 2; ++sl) {
        const short8 af0 = *(const short8*)&a0bf[m16][wave * 64 + sl * 32 + quad * 8];
        const short8 af1 = *(const short8*)&a1bf[m16][wave * 64 + sl * 32 + quad * 8];
        aA0 = __builtin_amdgcn_mfma_f32_16x16x32_bf16(af0, wf0[sl][0], aA0, 0, 0, 0);
        aA1 = __builtin_amdgcn_mfma_f32_16x16x32_bf16(af0, wf0[sl][1], aA1, 0, 0, 0);
        aC0 = __builtin_amdgcn_mfma_f32_16x16x32_bf16(af0, wfA[sl][0], aC0, 0, 0, 0);
        aC1 = __builtin_amdgcn_mfma_f32_16x16x32_bf16(af0, wfA[sl][1], aC1, 0, 0, 0);
        aB0 = __builtin_amdgcn_mfma_f32_16x16x32_bf16(af1, wfB[sl][0], aB0, 0, 0, 0);
        aB1 = __builtin_amdgcn_mfma_f32_16x16x32_bf16(af1, wfB[sl][1], aB1, 0, 0, 0);
      }
      if (lane < 32) {
#pragma unroll
        for (int r = 0; r < 4; ++r) {
          partsA[wave][quad * 4 + r][m16]      = aA0[r];
          partsA[wave][quad * 4 + r][16 + m16] = aA1[r];
          partsB[wave][quad * 4 + r][m16]      = aB0[r];
          partsB[wave][quad * 4 + r][16 + m16] = aB1[r];
          partsC[wave][quad * 4 + r][m16]      = aC0[r];
          partsC[wave][quad * 4 + r][16 + m16] = aC1[r];
        }
      }
      if (wave < 2) {
        f32x4 ax0 = {0.f,0.f,0.f,0.f}, ax1 = {0.f,0.f,0.f,0.f};
        const short8 xf = *(const short8*)&xsb[m16][wave * 32 + quad * 8];
        ax0 = __builtin_amdgcn_mfma_f32_16x16x32_bf16(xf, wfx[0], ax0, 0, 0, 0);
        ax1 = __builtin_amdgcn_mfma_f32_16x16x32_bf16(xf, wfx[1], ax1, 0, 0, 0);
        if (lane < 32) {
#pragma unroll
          for (int r = 0; r < 4; ++r) {
            partsX[wave][quad * 4 + r][m16]      = ax0[r];
            partsX[wave][quad * 4 + r][16 + m16] = ax1[r];
          }
        }
      }
    }
    __syncthreads();                                    // b1

    // ===== parallel epilogues: waves 0-3 = L0 step s | waves 4-7 = L1 step s-1
    if (wave < 4) {
      if (s < T_SZ) {
        float sH = 0.f;
#pragma unroll
        for (int w = 0; w < 8; ++w) sH += partsA[w][ech][cl];
        const float sX = partsX[0][ech][cl] + partsX[1][ech][cl];
        const float z = ((s == 0) ? c0i : c0f) + r0 * sH - r0 * m0 * uw0 + sX;
        const float h0prev = (s == 0) ? 0.f : (v2prev0 - m0) * r0 * g0c + be0c;
        const float v2 = fast_tanh(z) + h0prev;
        v2prev0 = v2;
        const unsigned vb = f2b(v2);
        *ep_lds = (unsigned short)vb;
        const unsigned u01 = vb | (__shfl_down(vb, 1) << 16);
        const unsigned u23 = __shfl_down(u01, 2);
        if ((cl & 3) == 0)
          st_rlx((par ? pubpay1 : pubpay0), (ull)u01 | ((ull)u23 << 32));
        float S = v2, Q = v2 * v2;
#pragma unroll
        for (int off = 16; off; off >>= 1) {
          S += __shfl_down(S, off, 32); Q += __shfl_down(Q, off, 32);
        }
        if (cl == 0) {
          myS0 = S; myQ0 = Q;     // LDS write deferred past b2 (st0 still being read)
          st_rlx((par ? pubpst1 : pubpst0), packf2(S, Q));
        }
      }
    } else if (s >= 1) {
      float sB = 0.f, sC = 0.f;
#pragma unroll
      for (int w = 0; w < 8; ++w) { sB += partsB[w][ech][cl]; sC += partsC[w][ech][cl]; }
      const float z = ((s == 1) ? c1i : c1f) + r0 * sC - r0 * m0 * uw1
                      + r1p * sB - r1p * m1p * uh1;
      const float h1prev = (s == 1) ? 0.f : (v2prev1 - m1p) * r1p * g1c + be1c;
      const float v2 = fast_tanh(z) + h1prev;
      v2prev1 = v2;
      const unsigned vb = f2b(v2);
      *ep_lds = (unsigned short)vb;
      const unsigned u01 = vb | (__shfl_down(vb, 1) << 16);
      const unsigned u23 = __shfl_down(u01, 2);
      if ((cl & 3) == 0)
        st_rlx((par ? pubpay1 : pubpay0), (ull)u01 | ((ull)u23 << 32));
      float S = v2, Q = v2 * v2;
#pragma unroll
      for (int off = 16; off; off >>= 1) {
        S += __shfl_down(S, off, 32); Q += __shfl_down(Q, off, 32);
      }
      if (cl == 0) {
        myS1 = S; myQ1 = Q;
        st_rlx((par ? pubpst1 : pubpst0), packf2(S, Q));
      }
    }
    __syncthreads();                                    // b2 (drains publishes)
    if (tid == 0) st_flag(flags + blk * 16, (unsigned)(s + 1));
    if (s == T_SZ) break;

    // deferred own-stat LDS writes (read from slot s+1 hoist onward)
    if (cl == 0) {
      if (wave < 4)       st0[ech][p] = make_float2(myS0, myQ0);
      else if (s >= 1)    st1[ech][p] = make_float2(myS1, myQ1);
    }
    // x prefetch issue (consumed after b3 barrier next slot)
    float xv = 0.f;
    if (s + 1 < T_SZ) xv = *xptr;
    xptr += DD;

    // -------- per-wave rendezvous: this wave's 1-2 peers only --------
    if (two) {
      while (ld_flag(pf0) < (unsigned)(s + 1) || ld_flag(pf1) < (unsigned)(s + 1))
        __builtin_amdgcn_s_sleep(1);
    } else {
      while (ld_flag(pf0) < (unsigned)(s + 1)) __builtin_amdgcn_s_sleep(1);
    }

    // -------- register-staged gather: 5 loads then 5 LDS stores ------------
    {
      ull tv[5];
#pragma unroll
      for (int k = 0; k < 5; ++k) {
        const bool v = s ? gv[k] : gva0[k];
        tv[k] = 0;
        if (v) tv[k] = ld_rlx(par ? gp1[k] : gp0[k]);
      }
#pragma unroll
      for (int k = 0; k < 5; ++k) {
        const bool v = s ? gv[k] : gva0[k];
        if (v) *glw[k] = tv[k];
      }
    }
    if (s + 1 < T_SZ) xsb[wave][lane] = f2b(xv);
    __syncthreads();                                    // b3
  }

  // ============ head (p==0 blocks): out = LN(v2_1^{T-1}).Wfc + bfc ========
  // v2_1^{T-1} published at slot T with par = T&1 = 0.
  if (p == 0) {
    if (tid < 16) {
      const unsigned* pf = flags + (group * NBLK + tid) * 16;
      while (ld_flag(pf) < (unsigned)(T_SZ + 1)) __builtin_amdgcn_s_sleep(1);
    }
    __syncthreads();
    const int c = wave;   // wave handles chain c
    ull su = 0;
    if (lane < 16)
      su = ld_rlx(pst + (((size_t)(group * NBLK + lane) * 2 + 1) * 2 + 0) * NCH + c);
    float S = unpack_lo(su), Q = unpack_hi(su);
#pragma unroll
    for (int off = 32; off; off >>= 1) { S += __shfl_down(S, off); Q += __shfl_down(Q, off); }
    S = __shfl(S, 0); Q = __shfl(Q, 0);
    const float m1 = S * (1.f / HH);
    const float r1 = 1.f / sqrtf(Q * (1.f / HH) - m1 * m1 + 1e-5f);
    float o = 0.f;
#pragma unroll
    for (int it = 0; it < 2; ++it) {
      const int j2 = lane * 2 + it, pl = j2 >> 3, j = j2 & 7;
      ull u = ld_rlx(pay + ((((size_t)(group * NBLK + pl) * 2 + 1) * 2 + 0) * NCH + c) * 8 + j);
#pragma unroll
      for (int q = 0; q < 4; ++q) {
        const int col = pl * 32 + 4 * j + q;
        const float h = (b2f((unsigned short)(u >> (16 * q))) - m1) * r1 * g1v[col] + be1v[col];
        o += h * wfc[col];
      }
    }
#pragma unroll
    for (int off = 32; off; off >>= 1) o += __shfl_down(o, off);
    if (lane == 0) out[group * NCH + c] = o + bfc[0];
  }
}

extern "C" void kernel_launch(void* const* d_in, const int* in_sizes, int n_in,
                              void* d_out, int out_size, void* d_ws, size_t ws_size,
                              hipStream_t stream) {
  const float* x   = (const float*)d_in[0];
  const float* Wi0 = (const float*)d_in[1];
  const float* bi0 = (const float*)d_in[2];
  const float* Wh0 = (const float*)d_in[3];
  const float* bh0 = (const float*)d_in[4];
  const float* g0  = (const float*)d_in[5];
  const float* be0 = (const float*)d_in[6];
  const float* Wi1 = (const float*)d_in[7];
  const float* bi1 = (const float*)d_in[8];
  const float* Wh1 = (const float*)d_in[9];
  const float* bh1 = (const float*)d_in[10];
  const float* g1  = (const float*)d_in[11];
  const float* be1 = (const float*)d_in[12];
  const float* Wfc = (const float*)d_in[13];
  const float* bfc = (const float*)d_in[14];
  float* out = (float*)d_out;

  // ws: cvec 16KB | pay 512KB | pst 64KB | flags 16KB
  char* ws = (char*)d_ws;
  float* cvec     = (float*)(ws);
  ull* pay        = (ull*)(ws + 16384);
  ull* pst        = (ull*)(ws + 16384 + 524288);
  unsigned* flags = (unsigned*)(ws + 16384 + 524288 + 65536);

  prep_kernel<<<256, 256, 0, stream>>>(Wh0, Wi1, Wh1, bi0, bh0, bi1, bh1,
                                       g0, be0, g1, be1, cvec, flags);
  rnn_mfma<<<256, 512, 0, stream>>>(x, Wi0, Wh0, Wi1, Wh1, cvec,
                                    g0, be0, g1, be1, Wfc, bfc,
                                    pay, pst, flags, out);
}